// Round 2
// baseline (2221.827 us; speedup 1.0000x reference)
//
#include <hip/hip_runtime.h>
#include <stdint.h>

// out[b,o] = sum_i W[i,o] * I[i,b],  I = per-object concat [first|mid0|mid1|last].
// ROWS = 17408 = 136 chunks of 128 rows; each chunk lies in one source segment.
//
// R6 post-mortem: counted-vmcnt ring was NEUTRAL (412 vs 408) -> the limiter was
// never the per-stage drain. It is (a) block-count quantization: 1088 blocks at
// 512-resident capacity = 2.125 rounds executed as 3 -> 71% util ceiling, and
// (b) 143 MB of ws round-trip traffic, and (c) 40 ds_read/wave/stage of weight
// broadcast pressure.
//
// R7 (this): 8 chunk-groups x 64 b-tiles = EXACTLY 512 uniform blocks (2/CU,
// zero tail). Each block: 17 chunks x 128 rows x 64 b, register accumulation
// across chunks -> ws 71.3 MB -> 4 MB. Weights double-buffered (2x16 KB),
// prefetched one chunk ahead inside the counted-vmcnt stream; per-chunk weight
// refetch by 64 blocks is L2-resident (2.2 MB total). Lane layout 4b x 2o:
// per row 1 ds_read_b128 (x) + 1 ds_read_b64 (w, 16-way broadcast) for 8 FMAs.
// x staged by width-4 global_load_lds (row slice = 256 B), ring 3 x 8 KB.
// LDS = 32 KB w + 24 KB x = 56 KB -> 2 blocks/CU.
// Fixed harness overhead (1 GiB ws poison + input restore) ~= 260 us of dur_us.

#define BATCH  4096
#define OUTC   32
#define BTILE  64      // b-columns per block
#define NBT    64      // BATCH / BTILE
#define NGRP   8       // chunk groups
#define CPB    17      // chunks per block (136 / NGRP)
#define RS     32      // rows per pipeline stage
#define NSS    4       // stages per chunk (128 / RS)

__device__ __forceinline__ void dma16(const float* g, float* l) {
    __builtin_amdgcn_global_load_lds(
        (const __attribute__((address_space(1))) void*)g,
        (__attribute__((address_space(3))) void*)l, 16, 0, 0);
}
__device__ __forceinline__ void dma4(const float* g, float* l) {
    __builtin_amdgcn_global_load_lds(
        (const __attribute__((address_space(1))) void*)g,
        (__attribute__((address_space(3))) void*)l, 4, 0, 0);
}

// wait own DMAs to depth N, then block barrier, then pin scheduling.
#define PIPE_WAIT(N) do {                                   \
    asm volatile("s_waitcnt vmcnt(" #N ")" ::: "memory");   \
    __builtin_amdgcn_s_barrier();                           \
    __builtin_amdgcn_sched_barrier(0);                      \
} while (0)

// vmcnt bookkeeping (per wave; x-stage = 8 dma4, W = 4 dma16):
//   prologue issues: W0(4), x0(8), x1(8)
//   iter S issues x_{S+2}; at (c,ss=1) additionally W_{c+1} AFTER x_{4c+3}.
//   top of (c,0): outstanding [W_c:4, x_{4c}:8, x_{4c+1}:8]   -> vmcnt(8)
//   top of (c,1): [x:8, x:8]                                  -> vmcnt(8)
//   top of (c,2): [x:8, x:8, W:4]                             -> vmcnt(12)
//   top of (c,3): [x:8, W:4, x:8]                             -> vmcnt(12)
//   epilogue c=16 (no W17): (2) [x66,x67] -> vmcnt(8); (3) [x67] -> vmcnt(0)

__global__ __launch_bounds__(256, 2) void cwl_partial(
    const float* __restrict__ cf,   // (4,128,4096)
    const float* __restrict__ cm,   // (4,2,2048,4096)
    const float* __restrict__ cl,   // (4,128,4096)
    const float* __restrict__ w,    // (17408,32)
    float* __restrict__ ws)         // (NGRP,4096,32) = 4 MB
{
    __shared__ float wl[2][128 * OUTC];   // 2 x 16 KB weights (chunk dbuf)
    __shared__ float xl[3][RS * BTILE];   // 3 x 8 KB x ring

    const int bt   = blockIdx.x & (NBT - 1);
    const int grp  = blockIdx.x >> 6;
    const int tid  = threadIdx.x;
    const int wv   = tid >> 6;
    const int lane = tid & 63;
    const int bq   = (lane & 15) * 4;          // b-offset within tile
    const int op   = wv * 8 + (lane >> 4) * 2; // this thread's 2 outs

    auto chunk_src = [&](int c) -> const float* {
        const int chunk = grp * CPB + c;
        const int obj = chunk / 34;
        const int j   = chunk % 34;
        const float* s = (j == 0)  ? cf + (size_t)obj * 128 * BATCH
                       : (j == 33) ? cl + (size_t)obj * 128 * BATCH
                       : cm + ((size_t)obj * 4096 + (size_t)(j - 1) * 128) * BATCH;
        return s + bt * BTILE;
    };

    // stage = 32 rows x 64 floats; wave wv DMAs rows wv*8..wv*8+7 (8 dma4).
    auto issue_x = [&](const float* src, int r0, int sl) {
#pragma unroll
        for (int t = 0; t < 8; ++t) {
            const int r = wv * 8 + t;
            dma4(src + (size_t)(r0 + r) * BATCH + lane, &xl[sl][r * BTILE]);
        }
    };
    // chunk weights: 16 KB linear copy, 4 dma16 per wave.
    auto issue_w = [&](int c, int buf) {
        const float* wgc = w + (size_t)(grp * CPB + c) * 128 * OUTC;
#pragma unroll
        for (int t = 0; t < 4; ++t) {
            const int seg = wv * 4 + t;
            dma16(wgc + seg * 256 + lane * 4, &wl[buf][seg * 256]);
        }
    };

    float accG[8], accL[8];
#pragma unroll
    for (int k = 0; k < 8; ++k) { accG[k] = 0.f; accL[k] = 0.f; }

    auto compute = [&](int wbuf, int ss, int sl) {
        const float* xb = &xl[sl][bq];
        const float* wb = &wl[wbuf][ss * RS * OUTC + op];
#pragma unroll
        for (int r = 0; r < RS; ++r) {
            const float4 x  = *(const float4*)(xb + r * BTILE);
            const float2 wq = *(const float2*)(wb + r * OUTC);
            accL[0] = fmaf(x.x, wq.x, accL[0]);
            accL[1] = fmaf(x.x, wq.y, accL[1]);
            accL[2] = fmaf(x.y, wq.x, accL[2]);
            accL[3] = fmaf(x.y, wq.y, accL[3]);
            accL[4] = fmaf(x.z, wq.x, accL[4]);
            accL[5] = fmaf(x.z, wq.y, accL[5]);
            accL[6] = fmaf(x.w, wq.x, accL[6]);
            accL[7] = fmaf(x.w, wq.y, accL[7]);
        }
    };

    // ---- prologue: W0 + x stages 0,1 ----
    const float* srcC = chunk_src(0);
    const float* srcN = chunk_src(1);
    issue_w(0, 0);
    issue_x(srcC, 0,  0);
    issue_x(srcC, RS, 1);

    int cur = 0;   // ring slot of the stage about to be computed
    for (int c = 0; c < CPB - 1; ++c) {
        const int wbuf = c & 1;
        int isl;
        // ss = 0 : compute chunk c rows 0..31, prefetch rows 64..95
        PIPE_WAIT(8);
        isl = (cur == 0) ? 2 : cur - 1;
        issue_x(srcC, 2 * RS, isl);
        compute(wbuf, 0, cur);
        cur = (cur == 2) ? 0 : cur + 1;
        // ss = 1 : prefetch rows 96..127, then weights for chunk c+1
        PIPE_WAIT(8);
        isl = (cur == 0) ? 2 : cur - 1;
        issue_x(srcC, 3 * RS, isl);
        issue_w(c + 1, wbuf ^ 1);
        compute(wbuf, 1, cur);
        cur = (cur == 2) ? 0 : cur + 1;
        // ss = 2 : prefetch chunk c+1 rows 0..31
        PIPE_WAIT(12);
        isl = (cur == 0) ? 2 : cur - 1;
        issue_x(srcN, 0, isl);
        compute(wbuf, 2, cur);
        cur = (cur == 2) ? 0 : cur + 1;
        // ss = 3 : prefetch chunk c+1 rows 32..63
        PIPE_WAIT(12);
        isl = (cur == 0) ? 2 : cur - 1;
        issue_x(srcN, RS, isl);
        compute(wbuf, 3, cur);
        cur = (cur == 2) ? 0 : cur + 1;
        // fold chunk into the long accumulator (keeps per-element chains short)
#pragma unroll
        for (int k = 0; k < 8; ++k) { accG[k] += accL[k]; accL[k] = 0.f; }
        srcC = srcN;
        srcN = chunk_src((c + 2 <= CPB - 1) ? c + 2 : CPB - 1);
    }

    // ---- epilogue: chunk 16 (wbuf = 0), no further weight prefetch ----
    {
        int isl;
        PIPE_WAIT(8);
        isl = (cur == 0) ? 2 : cur - 1;
        issue_x(srcC, 2 * RS, isl);
        compute(0, 0, cur);
        cur = (cur == 2) ? 0 : cur + 1;
        PIPE_WAIT(8);
        isl = (cur == 0) ? 2 : cur - 1;
        issue_x(srcC, 3 * RS, isl);
        compute(0, 1, cur);
        cur = (cur == 2) ? 0 : cur + 1;
        PIPE_WAIT(8);
        compute(0, 2, cur);
        cur = (cur == 2) ? 0 : cur + 1;
        PIPE_WAIT(0);
        compute(0, 3, cur);
#pragma unroll
        for (int k = 0; k < 8; ++k) accG[k] += accL[k];
    }

    // ---- store: ws[grp][b][o], float2 per (b, o-pair) ----
    const int b0 = bt * BTILE + (lane & 15) * 4;
#pragma unroll
    for (int bi = 0; bi < 4; ++bi) {
        float2* dst = (float2*)(ws + ((size_t)grp * BATCH + (b0 + bi)) * OUTC + op);
        *dst = make_float2(accG[bi * 2 + 0], accG[bi * 2 + 1]);
    }
}

// out[t] = sum_g ws[g][t]; 8 coalesced reads, L2-resident.
__global__ __launch_bounds__(256) void cwl_reduce(
    const float* __restrict__ ws, float* __restrict__ out)
{
    const int t = blockIdx.x * 256 + threadIdx.x;   // 0..131071
    float s = 0.f;
#pragma unroll
    for (int g = 0; g < NGRP; ++g)
        s += ws[(size_t)g * (BATCH * OUTC) + t];
    out[t] = s;
}

extern "C" void kernel_launch(void* const* d_in, const int* in_sizes, int n_in,
                              void* d_out, int out_size, void* d_ws, size_t ws_size,
                              hipStream_t stream)
{
    const float* cf = (const float*)d_in[0];
    const float* cm = (const float*)d_in[1];
    const float* cl = (const float*)d_in[2];
    const float* w  = (const float*)d_in[3];
    float* out = (float*)d_out;
    float* ws  = (float*)d_ws;   // 8*131072*4 = 4 MB used

    cwl_partial<<<dim3(NGRP * NBT), dim3(256), 0, stream>>>(cf, cm, cl, w, ws);
    cwl_reduce<<<dim3((BATCH * OUTC) / 256), dim3(256), 0, stream>>>(ws, out);
}

// Round 4
// 910.161 us; speedup vs baseline: 2.4411x; 2.4411x over previous
//
#include <hip/hip_runtime.h>
#include <stdint.h>

// out[b,o] = sum_i W[i,o] * I[i,b],  I = per-object concat [first|mid0|mid1|last].
// ROWS = 17408 = 136 chunks of 128 rows; chunk never crosses a source segment.
//
// R8 post-mortem (absmax 5.49): weight READ base dropped the g*128 row offset
// -- row-groups 1..3 read weight row r4 instead of r4+g (3/4 of FMAs wrong).
// DMA-side swizzle, x path, vmcnt accounting, ring rotation all audit clean.
// R9 (this): one-line fix, wA = g*128 + ((wv*32) ^ (g<<4)); structure unchanged:
//   - 8 chunk-groups x 64 b-tiles = EXACTLY 512 uniform blocks (2/CU, no tail);
//   - register accumulation over 17 chunks -> ws 4 MB (was 71.3 MB);
//   - x: dma16-staged ring 3 x 8 KB, counted vmcnt (2/6), one ds_read_b128
//     per 4 rows per thread, zero duplication/conflict;
//   - w: 2 x 16 KB chunk dbuf, dma16 with XOR-pre-swizzled global source
//     (rule #21), broadcast reads on disjoint banks;
//   - row-group partials reduced by 2 shfl_xor at the end.
// LDS = 56 KB -> 2 blocks/CU. Ideal traffic ~292 MB read, 4 MB write.
// Fixed harness overhead (1 GiB ws poison + input restore) ~= 260 us of dur_us.

#define BATCH  4096
#define OUTC   32
#define BTILE  64      // b-columns per block
#define NBT    64      // BATCH / BTILE
#define NGRP   8       // chunk groups
#define CPB    17      // chunks per block
#define RS     32      // rows per x stage (8 KB)

__device__ __forceinline__ void dma16(const float* g, float* l) {
    __builtin_amdgcn_global_load_lds(
        (const __attribute__((address_space(1))) void*)g,
        (__attribute__((address_space(3))) void*)l, 16, 0, 0);
}

__device__ __forceinline__ const float* chunk_src(
    int chunk, int bt, const float* cf, const float* cm, const float* cl)
{
    const int obj = chunk / 34;
    const int j   = chunk % 34;
    const float* s = (j == 0)  ? cf + (size_t)obj * 128 * BATCH
                   : (j == 33) ? cl + (size_t)obj * 128 * BATCH
                   : cm + ((size_t)obj * 4096 + (size_t)(j - 1) * 128) * BATCH;
    return s + bt * BTILE;
}

// phase prologue: wait own DMAs to depth N, block barrier, pin scheduling.
#define PIPE(N) do {                                 \
    asm volatile("s_waitcnt vmcnt(" #N ")");         \
    __builtin_amdgcn_s_barrier();                    \
    __builtin_amdgcn_sched_barrier(0);               \
} while (0)

// x stage: 32 rows x 64 floats, 8 dma16 (2 per wave). Lane L of dma16 t:
// global row R0 + wv*8 + t*4 + (L>>4), cols (L&15)*4.. ; LDS linear row-major.
#define ISSUE_X(SRC, R0, SL) do {                                            \
    dma16((SRC) + (size_t)((R0) + wv8 + 0 + g) * BATCH + bq,                 \
          &xl[SL][(wv8 + 0) * BTILE]);                                       \
    dma16((SRC) + (size_t)((R0) + wv8 + 4 + g) * BATCH + bq,                 \
          &xl[SL][(wv8 + 4) * BTILE]);                                       \
} while (0)

// w chunk: 16 KB, 16 dma16 (4 per wave), global source pre-swizzled so that
// LDS byte X holds w byte X ^ ((row(X)&3)<<4), row(X)=X>>7.
#define ISSUE_W(C, BUF) do {                                                 \
    const float* wgc = w + (size_t)(grp * CPB + (C)) * (128 * OUTC);         \
    dma16(wgc + (wv4 + 0) * 256 + wsw, &wl[BUF][(wv4 + 0) * 256]);           \
    dma16(wgc + (wv4 + 1) * 256 + wsw, &wl[BUF][(wv4 + 1) * 256]);           \
    dma16(wgc + (wv4 + 2) * 256 + wsw, &wl[BUF][(wv4 + 2) * 256]);           \
    dma16(wgc + (wv4 + 3) * 256 + wsw, &wl[BUF][(wv4 + 3) * 256]);           \
} while (0)

// compute one 32-row stage: 8 x (1 x-b128 + 2 w-b128 + 32 fma).
// thread: rows (r4 + g), b = bq..bq+4, outs = wv*8..wv*8+8.
#define COMPUTE(WB, SS, SL) do {                                             \
    const float* xb  = &xl[SL][0] + lane * 4;                                \
    const char*  wp  = (const char*)&wl[WB][0] + (SS) * (32 * 128);          \
    const char*  wpa = wp + wA;                                              \
    const char*  wpb = wp + wB;                                              \
    _Pragma("unroll")                                                        \
    for (int r4 = 0; r4 < RS; r4 += 4) {                                     \
        const float4 x  = *(const float4*)(xb + r4 * 64);                    \
        const float4 w0 = *(const float4*)(wpa + r4 * 128);                  \
        const float4 w1 = *(const float4*)(wpb + r4 * 128);                  \
        acc[0][0] = fmaf(x.x, w0.x, acc[0][0]);                              \
        acc[0][1] = fmaf(x.y, w0.x, acc[0][1]);                              \
        acc[0][2] = fmaf(x.z, w0.x, acc[0][2]);                              \
        acc[0][3] = fmaf(x.w, w0.x, acc[0][3]);                              \
        acc[1][0] = fmaf(x.x, w0.y, acc[1][0]);                              \
        acc[1][1] = fmaf(x.y, w0.y, acc[1][1]);                              \
        acc[1][2] = fmaf(x.z, w0.y, acc[1][2]);                              \
        acc[1][3] = fmaf(x.w, w0.y, acc[1][3]);                              \
        acc[2][0] = fmaf(x.x, w0.z, acc[2][0]);                              \
        acc[2][1] = fmaf(x.y, w0.z, acc[2][1]);                              \
        acc[2][2] = fmaf(x.z, w0.z, acc[2][2]);                              \
        acc[2][3] = fmaf(x.w, w0.z, acc[2][3]);                              \
        acc[3][0] = fmaf(x.x, w0.w, acc[3][0]);                              \
        acc[3][1] = fmaf(x.y, w0.w, acc[3][1]);                              \
        acc[3][2] = fmaf(x.z, w0.w, acc[3][2]);                              \
        acc[3][3] = fmaf(x.w, w0.w, acc[3][3]);                              \
        acc[4][0] = fmaf(x.x, w1.x, acc[4][0]);                              \
        acc[4][1] = fmaf(x.y, w1.x, acc[4][1]);                              \
        acc[4][2] = fmaf(x.z, w1.x, acc[4][2]);                              \
        acc[4][3] = fmaf(x.w, w1.x, acc[4][3]);                              \
        acc[5][0] = fmaf(x.x, w1.y, acc[5][0]);                              \
        acc[5][1] = fmaf(x.y, w1.y, acc[5][1]);                              \
        acc[5][2] = fmaf(x.z, w1.y, acc[5][2]);                              \
        acc[5][3] = fmaf(x.w, w1.y, acc[5][3]);                              \
        acc[6][0] = fmaf(x.x, w1.z, acc[6][0]);                              \
        acc[6][1] = fmaf(x.y, w1.z, acc[6][1]);                              \
        acc[6][2] = fmaf(x.z, w1.z, acc[6][2]);                              \
        acc[6][3] = fmaf(x.w, w1.z, acc[6][3]);                              \
        acc[7][0] = fmaf(x.x, w1.w, acc[7][0]);                              \
        acc[7][1] = fmaf(x.y, w1.w, acc[7][1]);                              \
        acc[7][2] = fmaf(x.z, w1.w, acc[7][2]);                              \
        acc[7][3] = fmaf(x.w, w1.w, acc[7][3]);                              \
    }                                                                        \
} while (0)

#define NEXT_SLOT(CUR) ((CUR) == 2 ? 0 : (CUR) + 1)
#define PREF_SLOT(CUR) (((CUR) + 2) >= 3 ? (CUR) - 1 : (CUR) + 2)

__global__ __launch_bounds__(256, 2) void cwl_partial(
    const float* __restrict__ cf,   // (4,128,4096)
    const float* __restrict__ cm,   // (4,2,2048,4096)
    const float* __restrict__ cl,   // (4,128,4096)
    const float* __restrict__ w,    // (17408,32)
    float* __restrict__ ws)         // (NGRP,4096,32) = 4 MB
{
    __shared__ __align__(16) float wl[2][128 * OUTC];   // 2 x 16 KB (chunk dbuf)
    __shared__ __align__(16) float xl[3][RS * BTILE];   // 3 x 8 KB x ring

    const int bt   = blockIdx.x & (NBT - 1);
    const int grp  = blockIdx.x >> 6;
    const int tid  = threadIdx.x;
    const int wv   = tid >> 6;
    const int lane = tid & 63;
    const int g    = lane >> 4;          // row-group 0..3
    const int bq   = (lane & 15) * 4;    // b-quad base
    const int wv8  = wv * 8;
    const int wv4  = wv * 4;

    // w read bases: thread reads w[row][wv*8 .. +8], row = r4+g.  That row's
    // data sits at LDS byte row*128 + (colbyte ^ (g<<4))  (row&3 == g since
    // r4 % 4 == 0).  R8 BUG was omitting the g*128 row term.
    const int wA = g * 128 + ((wv * 32) ^ (g << 4));
    const int wB = wA ^ 16;
    // w DMA source swizzle: lane L covers LDS bytes seg*1024 + L*16; global
    // float offset = seg*256 + ((L*16) ^ (((L>>3)&3)<<4)) / 4.
    const int wsw = ((lane * 16) ^ (((lane >> 3) & 3) << 4)) >> 2;

    float acc[8][4];
#pragma unroll
    for (int o = 0; o < 8; ++o)
#pragma unroll
        for (int b = 0; b < 4; ++b) acc[o][b] = 0.0f;

    // vmcnt bookkeeping (per wave; x stage = 2 ops, W chunk = 4 ops):
    //   prologue: W0(4), x0(2), x1(2) -> 8 outstanding
    //   (c,0): [W_c:4, x_s:2, x_s1:2]        -> vmcnt(2); issue x_s2
    //   (c,1): [x_s1:2, x_s2:2]              -> vmcnt(2); issue x_s3, W_{c+1}
    //   (c,2): [x_s2:2, x_s3:2, W:4]         -> vmcnt(6); issue x_s4
    //   (c,3): [x_s3:2, W:4, x_s4:2]         -> vmcnt(6); issue x_s5
    //   epilogue c=16: (0) vmcnt(2); (1) vmcnt(2); (2) vmcnt(2); (3) vmcnt(0)
    const float* srcC = chunk_src(grp * CPB + 0, bt, cf, cm, cl);
    const float* srcN = chunk_src(grp * CPB + 1, bt, cf, cm, cl);
    ISSUE_W(0, 0);
    ISSUE_X(srcC, 0,  0);
    ISSUE_X(srcC, RS, 1);

    int cur = 0;
    for (int c = 0; c < CPB - 1; ++c) {
        const int wb = c & 1;
        int nsl;
        PIPE(2);
        nsl = PREF_SLOT(cur);
        ISSUE_X(srcC, 2 * RS, nsl);
        COMPUTE(wb, 0, cur);
        cur = NEXT_SLOT(cur);

        PIPE(2);
        nsl = PREF_SLOT(cur);
        ISSUE_X(srcC, 3 * RS, nsl);
        ISSUE_W(c + 1, wb ^ 1);
        COMPUTE(wb, 1, cur);
        cur = NEXT_SLOT(cur);

        PIPE(6);
        nsl = PREF_SLOT(cur);
        ISSUE_X(srcN, 0, nsl);
        COMPUTE(wb, 2, cur);
        cur = NEXT_SLOT(cur);

        PIPE(6);
        nsl = PREF_SLOT(cur);
        ISSUE_X(srcN, RS, nsl);
        COMPUTE(wb, 3, cur);
        cur = NEXT_SLOT(cur);

        srcC = srcN;
        const int c2 = (c + 2 <= CPB - 1) ? c + 2 : CPB - 1;
        srcN = chunk_src(grp * CPB + c2, bt, cf, cm, cl);
    }

    // epilogue: chunk 16 (wbuf 0; W16 was issued at c=15 into buffer 0)
    {
        int nsl;
        PIPE(2);
        nsl = PREF_SLOT(cur);
        ISSUE_X(srcC, 2 * RS, nsl);
        COMPUTE(0, 0, cur);
        cur = NEXT_SLOT(cur);

        PIPE(2);
        nsl = PREF_SLOT(cur);
        ISSUE_X(srcC, 3 * RS, nsl);
        COMPUTE(0, 1, cur);
        cur = NEXT_SLOT(cur);

        PIPE(2);
        COMPUTE(0, 2, cur);
        cur = NEXT_SLOT(cur);

        PIPE(0);
        COMPUTE(0, 3, cur);
    }

    // reduce partials across the 4 row-groups (lanes L, L^16, L^32, L^48).
#pragma unroll
    for (int o = 0; o < 8; ++o)
#pragma unroll
        for (int b = 0; b < 4; ++b) {
            float v = acc[o][b];
            v += __shfl_xor(v, 16);
            v += __shfl_xor(v, 32);
            acc[o][b] = v;
        }

    // group 0 stores: ws[grp][bt*64 + (lane&15)*4 + bi][wv*8 .. +8]
    if (g == 0) {
        const int b0 = bt * BTILE + (lane & 15) * 4;
#pragma unroll
        for (int bi = 0; bi < 4; ++bi) {
            float* dst = ws + ((size_t)grp * BATCH + (b0 + bi)) * OUTC + wv8;
            *(float4*)(dst)     = make_float4(acc[0][bi], acc[1][bi],
                                              acc[2][bi], acc[3][bi]);
            *(float4*)(dst + 4) = make_float4(acc[4][bi], acc[5][bi],
                                              acc[6][bi], acc[7][bi]);
        }
    }
}

// out[t] = sum_g ws[g][t]; 8 coalesced reads, L2-resident.
__global__ __launch_bounds__(256) void cwl_reduce(
    const float* __restrict__ ws, float* __restrict__ out)
{
    const int t = blockIdx.x * 256 + threadIdx.x;   // 0..131071
    float s = 0.f;
#pragma unroll
    for (int gi = 0; gi < NGRP; ++gi)
        s += ws[(size_t)gi * (BATCH * OUTC) + t];
    out[t] = s;
}

extern "C" void kernel_launch(void* const* d_in, const int* in_sizes, int n_in,
                              void* d_out, int out_size, void* d_ws, size_t ws_size,
                              hipStream_t stream)
{
    const float* cf = (const float*)d_in[0];
    const float* cm = (const float*)d_in[1];
    const float* cl = (const float*)d_in[2];
    const float* w  = (const float*)d_in[3];
    float* out = (float*)d_out;
    float* ws  = (float*)d_ws;   // 8*131072*4 = 4 MB used

    cwl_partial<<<dim3(NGRP * NBT), dim3(256), 0, stream>>>(cf, cm, cl, w, ws);
    cwl_reduce<<<dim3((BATCH * OUTC) / 256), dim3(256), 0, stream>>>(ws, out);
}